// Round 3
// baseline (65.756 us; speedup 1.0000x reference)
//
#include <hip/hip_runtime.h>
#include <math.h>

#define MAX_SHIFT 128
#define S_TOTAL   257
#define SGB       5                    // shifts per block: s = 4*sg .. 4*sg+4 (overlap 1)
#define NSG       64                   // 64 shift-groups cover s = 0..256
#define VY        8                    // consecutive t-elements per thread per iter
#define BLOCK     1024                 // 16 waves; 2 blocks/CU -> 8 waves/SIMD
#define NW        (BLOCK / 64)
#define NQ        (SGB + 4)            // 5 cross + W, W2, Sy, Syy
#define WIN       (VY + SGB - 1)       // 12-float x window per thread-iter

// Evidence through round 2: kernel time is invariant to L2 locality and load
// count, but round 1's 256-thread/8-wave-per-SIMD variant ran ~2x faster
// (masked by +10us/node launch overhead of its second dispatch). Diagnosis:
// latency-bound (cold caches after the 256 MiB poison fill + post-fill clock
// ramp); the levers are waves/SIMD and serial depth per thread, NOT bandwidth.
// This version gets 8 waves/SIMD in ONE dispatch by splitting shifts finer
// instead of splitting time (which would need a cross-block combine):
//   64 sg-groups x 5 shifts x 8 bc = 512 blocks x 1024 thr = 2 blocks/CU
//   __launch_bounds__(1024, 8) -> VGPR <= 64 (live set ~29 floats, fits).
// Per-thread serial work drops 416 -> 288 VALU ops; window = 12 floats =
// 3 aligned float4 (d0 = 4sg-128 keeps 16B alignment). Retained from r2:
// XCD-aware bc = id&7 (one bc per XCD L2), window-sum W/W2 with per-shift
// edge correction (no separate full-range x loads).
__global__ __launch_bounds__(BLOCK, 8) void spc_kernel(const float* __restrict__ x,
                                                       const float* __restrict__ y,
                                                       float* __restrict__ out,
                                                       int T, int BC) {
    const int bc  = blockIdx.x & 7;        // one bc per XCD (id % 8 round-robin)
    const int sg  = blockIdx.x >> 3;       // shift group 0..63
    const int s0  = sg * 4;
    const int d0  = s0 - MAX_SHIFT;        // multiple of 4 -> 16B-aligned windows
    const int tid = threadIdx.x;
    const float* xb = x + (size_t)bc * T;
    const float* yb = y + (size_t)bc * T;

    float acc[SGB];
#pragma unroll
    for (int j = 0; j < SGB; ++j) acc[j] = 0.f;
    float w = 0.f, w2 = 0.f, sy = 0.f, syy = 0.f;

    // main loop: 4 trips of 8 t-elements per thread
    for (int t = tid * VY; t < T; t += BLOCK * VY) {
        float yv[VY], xw[WIN];             // window covers e+j for e<8, j<5
        *(float4*)(yv)     = *(const float4*)(yb + t);
        *(float4*)(yv + 4) = *(const float4*)(yb + t + 4);

        const int g0 = t + d0;
        if (g0 >= 0 && g0 + WIN <= T) {    // interior: 3 aligned float4 loads
#pragma unroll
            for (int i = 0; i < WIN / 4; ++i)
                *(float4*)(xw + 4 * i) = *(const float4*)(xb + g0 + 4 * i);
        } else {                           // boundary: guarded scalar loads (zero-pad)
#pragma unroll
            for (int i = 0; i < WIN; ++i) {
                int g = g0 + i;
                xw[i] = (g >= 0 && g < T) ? xb[g] : 0.f;
            }
        }

#pragma unroll
        for (int e = 0; e < VY; ++e) {
            const float yvv = yv[e];
#pragma unroll
            for (int j = 0; j < SGB; ++j)
                acc[j] = fmaf(xw[e + j], yvv, acc[j]);   // compile-time indices
            sy += yvv;   syy = fmaf(yvv, yvv, syy);
            w  += xw[e]; w2  = fmaf(xw[e], xw[e], w2);   // window sums (shift j=0)
        }
    }

    // ---- wave-level reductions of the 9 partials ----
    __shared__ float red[NQ][NW];
    __shared__ float tot[NQ];
    const int lane = tid & 63, wave = tid >> 6;
#pragma unroll
    for (int j = 0; j < SGB; ++j) {
        float v = acc[j];
        for (int off = 32; off; off >>= 1) v += __shfl_down(v, off, 64);
        if (lane == 0) red[j][wave] = v;
    }
    {
        float v4[4] = {w, w2, sy, syy};
#pragma unroll
        for (int q = 0; q < 4; ++q) {
            float v = v4[q];
            for (int off = 32; off; off >>= 1) v += __shfl_down(v, off, 64);
            if (lane == 0) red[SGB + q][wave] = v;
        }
    }
    __syncthreads();

    if (tid < NQ) {
        float v = 0.f;
#pragma unroll
        for (int wv = 0; wv < NW; ++wv) v += red[tid][wv];
        tot[tid] = v;
    }
    __syncthreads();

    // ---- finalize: blocks write j=0..3; sg==63 also writes j=4 (s=256) ----
    if (tid < SGB && (tid < SGB - 1 || sg == NSG - 1)) {
        const int s = s0 + tid;
        // edge correction: Sw(shift j) differs from W by <=4 elements at one end.
        // d0>=0: windows drop a prefix of x starting at d0 (tail is zero-pad);
        // d0<0:  windows gain a suffix of x ending at T+d0+j (head is zero-pad).
        float ev[4];
        const float* bp = xb + ((d0 >= 0) ? d0 : T + d0);   // 16B-aligned
        *(float4*)(ev) = *(const float4*)(bp);
        float es = 0.f, es2 = 0.f;
#pragma unroll
        for (int i = 0; i < SGB - 1; ++i)
            if (i < tid) { es += ev[i]; es2 = fmaf(ev[i], ev[i], es2); }

        const float W   = tot[SGB + 0];
        const float W2  = tot[SGB + 1];
        const float Sy  = tot[SGB + 2];
        const float Syy = tot[SGB + 3];
        const float Sw  = (d0 >= 0) ? (W  - es)  : (W  + es);
        const float Sw2 = (d0 >= 0) ? (W2 - es2) : (W2 + es2);

        const float invT  = 1.0f / (float)T;
        const float cr    = tot[tid];
        const float corr  = cr  - Sw * Sy * invT;
        const float normx = Sw2 - Sw * Sw * invT;
        const float normy = Syy - Sy * Sy * invT;
        out[(size_t)s * BC + bc] = corr / sqrtf(normx * normy);
    }
}

extern "C" void kernel_launch(void* const* d_in, const int* in_sizes, int n_in,
                              void* d_out, int out_size, void* d_ws, size_t ws_size,
                              hipStream_t stream) {
    const float* x = (const float*)d_in[0];
    const float* y = (const float*)d_in[1];
    float* out = (float*)d_out;

    const int BC = out_size / S_TOTAL;   // 8
    const int T  = in_sizes[0] / BC;     // 32768

    spc_kernel<<<dim3(NSG * BC), BLOCK, 0, stream>>>(x, y, out, T, BC);
}